// Round 4
// baseline (354.862 us; speedup 1.0000x reference)
//
#include <hip/hip_runtime.h>
#include <hip/hip_bf16.h>

#define NPTS 100000
#define NPTS_PAD 100096
#define DHID 512
#define EPSV 1e-5f

typedef __bf16 bf16;
typedef __attribute__((ext_vector_type(8))) __bf16 bf16x8;
typedef __attribute__((ext_vector_type(4))) __bf16 bf16x4;
typedef __attribute__((ext_vector_type(4))) float f32x4;

// ---- workspace layout (bytes) ----
// All operands k-tiled: Xp/Hp = [kt][NPTS_PAD][32] bf16, Wp = [kt][512][32] bf16
#define OFF_INBF   0UL            // 4*100096*32*2  = 25,624,576
#define OFF_W0     25624576UL     // 4*512*32*2     = 131,072
#define OFF_W1     25755648UL     // 16*512*32*2    = 524,288
#define OFF_W2     26279936UL     // 524,288
#define OFF_C0     26804224UL     // 512*4
#define OFF_C1     26806272UL
#define OFF_C2     26808320UL
#define OFF_PARTS  26810368UL     // 1563*512*4 = 3,201,024
#define OFF_PARTS2 30011392UL     // 64*512*4
#define OFF_PARTS3 30142464UL     // 8*512*4
#define OFF_H1     30158848UL     // 16*100096*32*2 = 102,498,304
#define OFF_H2     132657152UL    // 102,498,304  (end 235,155,456)

typedef const __attribute__((address_space(1))) unsigned int* gp_t;
typedef __attribute__((address_space(3))) unsigned int* lp_t;

__device__ __forceinline__ void async_copy16(const void* g, void* l) {
    __builtin_amdgcn_global_load_lds((gp_t)g, (lp_t)l, 16, 0, 0);
}

// ---------- prep: fp32 [NPTS][128] -> packed bf16 [4][NPTS_PAD][32] ----------
__global__ __launch_bounds__(256) void cvt_pack_kernel(const float* __restrict__ in,
                                                       bf16* __restrict__ out) {
    long total = (long)NPTS * 4;
    long stride = (long)gridDim.x * blockDim.x;
    for (long idx = (long)blockIdx.x * blockDim.x + threadIdx.x; idx < total; idx += stride) {
        int kt = (int)(idx / NPTS);
        long r = idx - (long)kt * NPTS;
        const float4* src = (const float4*)(in + r * 128 + kt * 32);
        bf16* dst = out + ((long)kt * NPTS_PAD + r) * 32;
#pragma unroll
        for (int j = 0; j < 8; ++j) {
            float4 v = src[j];
            bf16x4 o = { (bf16)v.x, (bf16)v.y, (bf16)v.z, (bf16)v.w };
            *(bf16x4*)(dst + j * 4) = o;
        }
    }
}

// ---------- prep: packed W = bf16(A - B), [NK][512][32] ----------
__global__ __launch_bounds__(256) void wdiff_pack_kernel(const float* __restrict__ A,
                                                         const float* __restrict__ B,
                                                         bf16* __restrict__ Wp, int KD) {
    int NK = KD / 32;
    int total = 512 * NK;
    int idx = blockIdx.x * blockDim.x + threadIdx.x;
    if (idx >= total) return;
    int kt = idx / 512, row = idx - kt * 512;
    const float4* sa = (const float4*)(A + (long)row * KD + kt * 32);
    const float4* sb = (const float4*)(B + (long)row * KD + kt * 32);
    bf16* dst = Wp + ((long)kt * 512 + row) * 32;
#pragma unroll
    for (int j = 0; j < 8; ++j) {
        float4 a = sa[j], b = sb[j];
        bf16x4 o = { (bf16)(a.x - b.x), (bf16)(a.y - b.y), (bf16)(a.z - b.z), (bf16)(a.w - b.w) };
        *(bf16x4*)(dst + j * 4) = o;
    }
}

// ---------- colsum of in_set (fp32, deterministic 2-stage) ----------
__global__ __launch_bounds__(256) void colsum_in_kernel(const float* __restrict__ in,
                                                        float* __restrict__ parts) {
    __shared__ float sh[256];
    int t = threadIdx.x, blk = blockIdx.x;
    int c = t & 127, half = t >> 7;
    long rbeg = (long)blk * 196 + half;
    long rend = (long)(blk + 1) * 196; if (rend > NPTS) rend = NPTS;
    float s = 0.f;
    for (long r = rbeg; r < rend; r += 2) s += in[r * 128 + c];
    sh[t] = s;
    __syncthreads();
    if (t < 128) parts[blk * 128 + t] = sh[t] + sh[t + 128];
}

// ---------- generic partial reduce: parts[nparts][width] -> out[grid][width] ----------
__global__ void part_reduceW_kernel(const float* __restrict__ parts, int nparts, int width,
                                    int op, float* __restrict__ out) {
    int g = blockIdx.x, t = threadIdx.x;
    int chunk = (nparts + gridDim.x - 1) / gridDim.x;
    int b0 = g * chunk, b1 = b0 + chunk; if (b1 > nparts) b1 = nparts;
    float s = 0.f;  // identity 0 valid for max too: values are post-relu >= 0
    for (int b = b0; b < b1; ++b) {
        float v = parts[(long)b * width + t];
        s = (op == 0) ? (s + v) : fmaxf(s, v);
    }
    out[(long)g * width + t] = s;
}

// ---------- fold 8 partial rows + GEMV: out[j] = (fold_g p3[g][:]) . Bm[j][:] + bias ----------
__global__ __launch_bounds__(64) void gemv_fold_kernel(const float* __restrict__ p3, int dsum,
                                                       const float* __restrict__ Bm,
                                                       const float* __restrict__ bias, int op,
                                                       float* __restrict__ out) {
    int j = blockIdx.x, t = threadIdx.x;
    float acc = 0.f;
    for (int d = t; d < dsum; d += 64) {
        float s = 0.f;
#pragma unroll
        for (int g = 0; g < 8; ++g) {
            float v = p3[(long)g * dsum + d];
            s = (op == 0) ? (s + v) : fmaxf(s, v);
        }
        acc += s * Bm[(long)j * dsum + d];
    }
#pragma unroll
    for (int m = 32; m >= 1; m >>= 1) acc += __shfl_down(acc, m);
    if (t == 0) out[j] = acc + (bias ? bias[j] : 0.0f);
}

// ---------- fused layer: C = X@W^T (bf16 MFMA) + c ; LN ; relu ; store bf16 ; col-red ----------
// BM=128, BN=512, BK=32, 512 threads = 8 waves (2Mx4N). Double-buffered LDS + counted
// vmcnt(5). K-tiled operand layouts: every global_load_lds reads CONTIGUOUS memory
// (W chunk 32KB/kstep, X chunk 8KB/kstep) -> no L2-channel hotspots. XOR lane-permute
// (slot ^ (lane>>3)&3) stays within each row's 64B line; LDS read side identical to R3.
template<int KD, bool STORE, int REDOP>  // REDOP 0=sum, 1=max
__global__ __launch_bounds__(512, 2)
void layer_kernel(const bf16* __restrict__ Xp, const bf16* __restrict__ Wp,
                  const float* __restrict__ cvec, const float* __restrict__ gvec,
                  const float* __restrict__ bvec, bf16* __restrict__ Hout,
                  float* __restrict__ red_out) {
    static_assert(KD % 32 == 0, "");
    constexpr int NK = KD / 32;
    // per buffer: Xs[128][32] bf16 = 8192 B, Ws[512][32] bf16 = 32768 B
    __shared__ __align__(128) char smem[2 * 40960];

    const int t = threadIdx.x;
    const int lane = t & 63;
    const int wid = t >> 6;          // 0..7
    const int wm = wid >> 2;         // 0..1  (M half: 64 rows)
    const int wn = wid & 3;          // 0..3  (N quarter: 128 cols)
    const int ln15 = lane & 15;
    const int lg = lane >> 4;        // 0..3
    const long row0 = (long)blockIdx.x * 128;

    f32x4 acc[4][8];
#pragma unroll
    for (int i = 0; i < 4; ++i)
#pragma unroll
        for (int j = 0; j < 8; ++j) acc[i][j] = (f32x4){0.f, 0.f, 0.f, 0.f};

    // ---- staging geometry (all-contiguous sources) ----
    const int l4 = lane >> 2;                       // row-within-16
    const int soff = ((lane & 3) ^ ((lane >> 3) & 3)) * 16;   // permuted 16B slot in row's 64B
    const char* Xbase = (const char*)Xp + (row0 + wid * 16 + l4) * 64 + soff;
    const char* Wbase = (const char*)Wp + (wid * 4096 + l4 * 64) + soff;

    auto stage = [&](int ks) {
        char* Xs = smem + (ks & 1) * 40960;
        char* Ws = Xs + 8192;
        async_copy16(Xbase + (long)ks * (NPTS_PAD * 64), Xs + wid * 1024 + lane * 16);
#pragma unroll
        for (int q = 0; q < 4; ++q)
            async_copy16(Wbase + ks * 32768 + q * 1024,
                         Ws + wid * 4096 + q * 1024 + lane * 16);
    };

    // prologue: 2 tiles in flight (10 outstanding vmem per thread)
    stage(0);
    stage(1);

#pragma unroll
    for (int ks = 0; ks < NK; ++ks) {
        // wait for tile ks only (tile ks+1's 5 loads stay in flight)
        if (ks < NK - 1) asm volatile("s_waitcnt vmcnt(5)" ::: "memory");
        else             asm volatile("s_waitcnt vmcnt(0)" ::: "memory");
        __builtin_amdgcn_s_barrier();

        const char* Xs = smem + (ks & 1) * 40960;
        const char* Ws = Xs + 8192;
        bf16x8 a[4], b[8];
#pragma unroll
        for (int fm = 0; fm < 4; ++fm) {
            int r = wm * 64 + fm * 16 + ln15;
            a[fm] = *(const bf16x8*)(Xs + r * 64 + ((lg ^ ((r >> 1) & 3)) * 16));
        }
#pragma unroll
        for (int fn = 0; fn < 8; ++fn) {
            int r = wn * 128 + fn * 16 + ln15;
            b[fn] = *(const bf16x8*)(Ws + r * 64 + ((lg ^ ((r >> 1) & 3)) * 16));
        }
#pragma unroll
        for (int fm = 0; fm < 4; ++fm)
#pragma unroll
            for (int fn = 0; fn < 8; ++fn)
                acc[fm][fn] = __builtin_amdgcn_mfma_f32_16x16x32_bf16(a[fm], b[fn], acc[fm][fn], 0, 0, 0);

        // all this wave's LDS reads complete before signaling buffer-free
        asm volatile("s_waitcnt lgkmcnt(0)" ::: "memory");
        __builtin_amdgcn_sched_barrier(0);
        __builtin_amdgcn_s_barrier();
        __builtin_amdgcn_sched_barrier(0);
        if (ks + 2 < NK) stage(ks + 2);
    }

    // ---------------- epilogue (reuses buf0 region of LDS) ----------------
    float* lnred_s = (float*)smem;            // [128][4]
    float* lnred_q = (float*)(smem + 2048);   // [128][4]
    float* lnmv    = (float*)(smem + 4096);   // [128][2]
    float* csred   = (float*)(smem + 5120);   // [2][512]

    // per-lane column constants (8 cols: wn*128 + fn*16 + ln15)
    const int cbase = wn * 128 + ln15;
    float cv[8], gv[8], bv[8];
#pragma unroll
    for (int fn = 0; fn < 8; ++fn) {
        int col = cbase + fn * 16;
        cv[fn] = cvec[col]; gv[fn] = gvec[col]; bv[fn] = bvec[col];
    }

    // add the broadcast c-vector (fp32-exact common term)
#pragma unroll
    for (int fm = 0; fm < 4; ++fm)
#pragma unroll
        for (int fn = 0; fn < 8; ++fn) acc[fm][fn] += cv[fn];

    // per-row sum / sumsq over this wave's 128 cols (shfl tree within 16-lane group)
    float rs[16], rq[16];
#pragma unroll
    for (int fm = 0; fm < 4; ++fm)
#pragma unroll
        for (int j = 0; j < 4; ++j) {
            float s = 0.f, q = 0.f;
#pragma unroll
            for (int fn = 0; fn < 8; ++fn) {
                float x = acc[fm][fn][j];
                s += x; q += x * x;
            }
            rs[fm * 4 + j] = s; rq[fm * 4 + j] = q;
        }
#pragma unroll
    for (int m = 1; m < 16; m <<= 1)
#pragma unroll
        for (int i = 0; i < 16; ++i) {
            rs[i] += __shfl_xor(rs[i], m);
            rq[i] += __shfl_xor(rq[i], m);
        }
    if (ln15 == 0) {
#pragma unroll
        for (int fm = 0; fm < 4; ++fm)
#pragma unroll
            for (int j = 0; j < 4; ++j) {
                int row = wm * 64 + fm * 16 + lg * 4 + j;
                lnred_s[row * 4 + wn] = rs[fm * 4 + j];
                lnred_q[row * 4 + wn] = rq[fm * 4 + j];
            }
    }
    __syncthreads();
    if (t < 128) {
        float s = lnred_s[t * 4] + lnred_s[t * 4 + 1] + lnred_s[t * 4 + 2] + lnred_s[t * 4 + 3];
        float q = lnred_q[t * 4] + lnred_q[t * 4 + 1] + lnred_q[t * 4 + 2] + lnred_q[t * 4 + 3];
        float mu = s * (1.0f / 512.0f);
        float var = q * (1.0f / 512.0f) - mu * mu;
        lnmv[t * 2] = mu;
        lnmv[t * 2 + 1] = rsqrtf(var + EPSV);
    }
    __syncthreads();

    // normalize + relu + (store bf16 packed) ; invalid rows forced to 0 (masked)
#pragma unroll
    for (int fm = 0; fm < 4; ++fm)
#pragma unroll
        for (int j = 0; j < 4; ++j) {
            int rloc = wm * 64 + fm * 16 + lg * 4 + j;
            long rglob = row0 + rloc;
            bool ok = rglob < NPTS;
            float mu = lnmv[rloc * 2], rstd = lnmv[rloc * 2 + 1];
#pragma unroll
            for (int fn = 0; fn < 8; ++fn) {
                float y = fmaxf((acc[fm][fn][j] - mu) * rstd * gv[fn] + bv[fn], 0.0f);
                acc[fm][fn][j] = ok ? y : 0.0f;
            }
            if (STORE && ok) {
#pragma unroll
                for (int fn = 0; fn < 8; ++fn) {
                    int kt = wn * 4 + (fn >> 1);
                    Hout[((long)kt * NPTS_PAD + rglob) * 32 + (fn & 1) * 16 + ln15] =
                        (bf16)acc[fm][fn][j];
                }
            }
        }

    // column partials over the block's 128 rows (sum or max)
    float cp[8];
#pragma unroll
    for (int fn = 0; fn < 8; ++fn) {
        float p = 0.f;
#pragma unroll
        for (int fm = 0; fm < 4; ++fm)
#pragma unroll
            for (int j = 0; j < 4; ++j) {
                float v = acc[fm][fn][j];
                p = (REDOP == 0) ? (p + v) : fmaxf(p, v);
            }
        cp[fn] = p;
    }
#pragma unroll
    for (int m = 16; m < 64; m <<= 1)
#pragma unroll
        for (int fn = 0; fn < 8; ++fn) {
            float o = __shfl_xor(cp[fn], m);
            cp[fn] = (REDOP == 0) ? (cp[fn] + o) : fmaxf(cp[fn], o);
        }
    if (lg == 0) {
#pragma unroll
        for (int fn = 0; fn < 8; ++fn)
            csred[wm * 512 + wn * 128 + fn * 16 + ln15] = cp[fn];
    }
    __syncthreads();
    {
        float a0 = csred[t], a1 = csred[512 + t];
        red_out[(long)blockIdx.x * 512 + t] = (REDOP == 0) ? (a0 + a1) : fmaxf(a0, a1);
    }
}

extern "C" void kernel_launch(void* const* d_in, const int* in_sizes, int n_in,
                              void* d_out, int out_size, void* d_ws, size_t ws_size,
                              hipStream_t stream) {
    const float* in_set = (const float*)d_in[0];
    const float* A0 = (const float*)d_in[1];
    const float* B0 = (const float*)d_in[2];
    const float* A1 = (const float*)d_in[3];
    const float* B1 = (const float*)d_in[4];
    const float* A2 = (const float*)d_in[5];
    const float* B2 = (const float*)d_in[6];
    const float* ga = (const float*)d_in[7];
    const float* be = (const float*)d_in[8];
    const float* ow = (const float*)d_in[9];
    const float* ob = (const float*)d_in[10];
    float* outp = (float*)d_out;
    char* ws = (char*)d_ws;

    bf16* in_bf = (bf16*)(ws + OFF_INBF);
    bf16* W0 = (bf16*)(ws + OFF_W0);
    bf16* W1 = (bf16*)(ws + OFF_W1);
    bf16* W2 = (bf16*)(ws + OFF_W2);
    float* c0 = (float*)(ws + OFF_C0);
    float* c1 = (float*)(ws + OFF_C1);
    float* c2 = (float*)(ws + OFF_C2);
    float* parts = (float*)(ws + OFF_PARTS);
    float* parts2 = (float*)(ws + OFF_PARTS2);
    float* parts3 = (float*)(ws + OFF_PARTS3);
    bf16* h1 = (bf16*)(ws + OFF_H1);
    bf16* h2 = (bf16*)(ws + OFF_H2);

    const int nblk = (NPTS + 127) / 128;  // 782

    cvt_pack_kernel<<<2048, 256, 0, stream>>>(in_set, in_bf);
    wdiff_pack_kernel<<<8, 256, 0, stream>>>(A0, B0, W0, 128);
    wdiff_pack_kernel<<<32, 256, 0, stream>>>(A1, B1, W1, 512);
    wdiff_pack_kernel<<<32, 256, 0, stream>>>(A2, B2, W2, 512);

    // c0 = colsum(in_set) @ B0^T  (all fp32 — the numerically critical path), wide+shallow
    colsum_in_kernel<<<512, 256, 0, stream>>>(in_set, parts);                       // [512][128]
    part_reduceW_kernel<<<64, 128, 0, stream>>>(parts, 512, 128, 0, parts2);        // [64][128]
    part_reduceW_kernel<<<8, 128, 0, stream>>>(parts2, 64, 128, 0, parts3);         // [8][128]
    gemv_fold_kernel<<<512, 64, 0, stream>>>(parts3, 128, B0, nullptr, 0, c0);

    layer_kernel<128, true, 0><<<nblk, 512, 0, stream>>>(in_bf, W0, c0, ga, be, h1, parts);
    part_reduceW_kernel<<<64, 512, 0, stream>>>(parts, nblk, 512, 0, parts2);
    part_reduceW_kernel<<<8, 512, 0, stream>>>(parts2, 64, 512, 0, parts3);
    gemv_fold_kernel<<<512, 64, 0, stream>>>(parts3, 512, B1, nullptr, 0, c1);

    layer_kernel<512, true, 0><<<nblk, 512, 0, stream>>>(h1, W1, c1, ga, be, h2, parts);
    part_reduceW_kernel<<<64, 512, 0, stream>>>(parts, nblk, 512, 0, parts2);
    part_reduceW_kernel<<<8, 512, 0, stream>>>(parts2, 64, 512, 0, parts3);
    gemv_fold_kernel<<<512, 64, 0, stream>>>(parts3, 512, B2, nullptr, 0, c2);

    // layer 2: no h3 store; fused column-max partials; final = (max-fold) @ ow^T + ob
    layer_kernel<512, false, 1><<<nblk, 512, 0, stream>>>(h2, W2, c2, ga, be, nullptr, parts);
    part_reduceW_kernel<<<64, 512, 0, stream>>>(parts, nblk, 512, 1, parts2);
    part_reduceW_kernel<<<8, 512, 0, stream>>>(parts2, 64, 512, 1, parts3);
    gemv_fold_kernel<<<256, 64, 0, stream>>>(parts3, 512, ow, ob, 1, outp);
}

// Round 5
// 354.781 us; speedup vs baseline: 1.0002x; 1.0002x over previous
//
#include <hip/hip_runtime.h>
#include <hip/hip_bf16.h>

#define NPTS 100000
#define NPTS_PAD 100096
#define DHID 512
#define EPSV 1e-5f

typedef __bf16 bf16;
typedef __attribute__((ext_vector_type(8))) __bf16 bf16x8;
typedef __attribute__((ext_vector_type(4))) __bf16 bf16x4;
typedef __attribute__((ext_vector_type(4))) float f32x4;

// ---- workspace layout (bytes) ----
// All operands k-tiled: Xp/Hp = [kt][NPTS_PAD][32] bf16, Wp = [kt][512][32] bf16
#define OFF_INBF   0UL            // 4*100096*32*2  = 25,624,576
#define OFF_W0     25624576UL     // 4*512*32*2     = 131,072
#define OFF_W1     25755648UL     // 16*512*32*2    = 524,288
#define OFF_W2     26279936UL     // 524,288
#define OFF_C0     26804224UL     // 512*4
#define OFF_C1     26806272UL
#define OFF_C2     26808320UL
#define OFF_PARTS  26810368UL     // 1563*512*4 = 3,201,024
#define OFF_PARTS2 30011392UL     // 64*512*4
#define OFF_PARTS3 30142464UL     // 8*512*4
#define OFF_H1     30158848UL     // 16*100096*32*2 = 102,498,304
#define OFF_H2     132657152UL    // 102,498,304  (end 235,155,456)

typedef const __attribute__((address_space(1))) unsigned int* gp_t;
typedef __attribute__((address_space(3))) unsigned int* lp_t;

__device__ __forceinline__ void async_copy16(const void* g, void* l) {
    __builtin_amdgcn_global_load_lds((gp_t)g, (lp_t)l, 16, 0, 0);
}

// ---------- prep: fp32 [NPTS][128] -> packed bf16 [4][NPTS_PAD][32] ----------
__global__ __launch_bounds__(256) void cvt_pack_kernel(const float* __restrict__ in,
                                                       bf16* __restrict__ out) {
    long total = (long)NPTS * 4;
    long stride = (long)gridDim.x * blockDim.x;
    for (long idx = (long)blockIdx.x * blockDim.x + threadIdx.x; idx < total; idx += stride) {
        int kt = (int)(idx / NPTS);
        long r = idx - (long)kt * NPTS;
        const float4* src = (const float4*)(in + r * 128 + kt * 32);
        bf16* dst = out + ((long)kt * NPTS_PAD + r) * 32;
#pragma unroll
        for (int j = 0; j < 8; ++j) {
            float4 v = src[j];
            bf16x4 o = { (bf16)v.x, (bf16)v.y, (bf16)v.z, (bf16)v.w };
            *(bf16x4*)(dst + j * 4) = o;
        }
    }
}

// ---------- prep: packed W = bf16(A - B), [NK][512][32] ----------
__global__ __launch_bounds__(256) void wdiff_pack_kernel(const float* __restrict__ A,
                                                         const float* __restrict__ B,
                                                         bf16* __restrict__ Wp, int KD) {
    int NK = KD / 32;
    int total = 512 * NK;
    int idx = blockIdx.x * blockDim.x + threadIdx.x;
    if (idx >= total) return;
    int kt = idx / 512, row = idx - kt * 512;
    const float4* sa = (const float4*)(A + (long)row * KD + kt * 32);
    const float4* sb = (const float4*)(B + (long)row * KD + kt * 32);
    bf16* dst = Wp + ((long)kt * 512 + row) * 32;
#pragma unroll
    for (int j = 0; j < 8; ++j) {
        float4 a = sa[j], b = sb[j];
        bf16x4 o = { (bf16)(a.x - b.x), (bf16)(a.y - b.y), (bf16)(a.z - b.z), (bf16)(a.w - b.w) };
        *(bf16x4*)(dst + j * 4) = o;
    }
}

// ---------- colsum of in_set (fp32, deterministic 2-stage) ----------
__global__ __launch_bounds__(256) void colsum_in_kernel(const float* __restrict__ in,
                                                        float* __restrict__ parts) {
    __shared__ float sh[256];
    int t = threadIdx.x, blk = blockIdx.x;
    int c = t & 127, half = t >> 7;
    long rbeg = (long)blk * 196 + half;
    long rend = (long)(blk + 1) * 196; if (rend > NPTS) rend = NPTS;
    float s = 0.f;
    for (long r = rbeg; r < rend; r += 2) s += in[r * 128 + c];
    sh[t] = s;
    __syncthreads();
    if (t < 128) parts[blk * 128 + t] = sh[t] + sh[t + 128];
}

// ---------- generic partial reduce: parts[nparts][width] -> out[grid][width] ----------
__global__ void part_reduceW_kernel(const float* __restrict__ parts, int nparts, int width,
                                    int op, float* __restrict__ out) {
    int g = blockIdx.x, t = threadIdx.x;
    int chunk = (nparts + gridDim.x - 1) / gridDim.x;
    int b0 = g * chunk, b1 = b0 + chunk; if (b1 > nparts) b1 = nparts;
    float s = 0.f;  // identity 0 valid for max too: values are post-relu >= 0
    for (int b = b0; b < b1; ++b) {
        float v = parts[(long)b * width + t];
        s = (op == 0) ? (s + v) : fmaxf(s, v);
    }
    out[(long)g * width + t] = s;
}

// ---------- fold 8 partial rows + GEMV: out[j] = (fold_g p3[g][:]) . Bm[j][:] + bias ----------
__global__ __launch_bounds__(64) void gemv_fold_kernel(const float* __restrict__ p3, int dsum,
                                                       const float* __restrict__ Bm,
                                                       const float* __restrict__ bias, int op,
                                                       float* __restrict__ out) {
    int j = blockIdx.x, t = threadIdx.x;
    float acc = 0.f;
    for (int d = t; d < dsum; d += 64) {
        float s = 0.f;
#pragma unroll
        for (int g = 0; g < 8; ++g) {
            float v = p3[(long)g * dsum + d];
            s = (op == 0) ? (s + v) : fmaxf(s, v);
        }
        acc += s * Bm[(long)j * dsum + d];
    }
#pragma unroll
    for (int m = 32; m >= 1; m >>= 1) acc += __shfl_down(acc, m);
    if (t == 0) out[j] = acc + (bias ? bias[j] : 0.0f);
}

// ---------- fused layer: C = X@W^T (bf16 MFMA) + c ; LN ; relu ; store bf16 ; col-red ----------
// BM=128, BN=512, BK=32, 512 threads = 8 waves (2Mx4N). TRIPLE-buffered LDS (3 x 40KB =
// 120KB, 1 block/CU) with 2-iteration lookahead: prologue stages tiles 0,1,2; loop waits
// vmcnt(10) (tiles ks+1, ks+2 remain in flight across barriers), computes ks, stages ks+3.
// Issue->wait distance ~2 iterations covers global_load_lds latency. vmcnt ladder 10/5/0.
// K-tiled global layouts (contiguous staging chunks); XOR lane-permute within 64B rows.
template<int KD, bool STORE, int REDOP>  // REDOP 0=sum, 1=max
__global__ __launch_bounds__(512, 2)
void layer_kernel(const bf16* __restrict__ Xp, const bf16* __restrict__ Wp,
                  const float* __restrict__ cvec, const float* __restrict__ gvec,
                  const float* __restrict__ bvec, bf16* __restrict__ Hout,
                  float* __restrict__ red_out) {
    static_assert(KD % 32 == 0, "");
    constexpr int NK = KD / 32;
    // per buffer: Xs[128][32] bf16 = 8192 B, Ws[512][32] bf16 = 32768 B
    __shared__ __align__(128) char smem[3 * 40960];

    const int t = threadIdx.x;
    const int lane = t & 63;
    const int wid = t >> 6;          // 0..7
    const int wm = wid >> 2;         // 0..1  (M half: 64 rows)
    const int wn = wid & 3;          // 0..3  (N quarter: 128 cols)
    const int ln15 = lane & 15;
    const int lg = lane >> 4;        // 0..3
    const long row0 = (long)blockIdx.x * 128;

    f32x4 acc[4][8];
#pragma unroll
    for (int i = 0; i < 4; ++i)
#pragma unroll
        for (int j = 0; j < 8; ++j) acc[i][j] = (f32x4){0.f, 0.f, 0.f, 0.f};

    // ---- staging geometry (all-contiguous sources) ----
    const int l4 = lane >> 2;                       // row-within-16
    const int soff = ((lane & 3) ^ ((lane >> 3) & 3)) * 16;   // permuted 16B slot in row's 64B
    const char* Xbase = (const char*)Xp + (row0 + wid * 16 + l4) * 64 + soff;
    const char* Wbase = (const char*)Wp + (wid * 4096 + l4 * 64) + soff;

    auto stage = [&](int ks) {
        char* Xs = smem + (ks % 3) * 40960;
        char* Ws = Xs + 8192;
        async_copy16(Xbase + (long)ks * (NPTS_PAD * 64), Xs + wid * 1024 + lane * 16);
#pragma unroll
        for (int q = 0; q < 4; ++q)
            async_copy16(Wbase + ks * 32768 + q * 1024,
                         Ws + wid * 4096 + q * 1024 + lane * 16);
    };

    // prologue: 3 tiles in flight (15 outstanding vmem per thread)
    stage(0);
    stage(1);
    if (NK > 2) stage(2);

#pragma unroll
    for (int ks = 0; ks < NK; ++ks) {
        // wait tile ks only; tiles ks+1, ks+2 stay in flight across the barriers (T4)
        if (ks <= NK - 3)      asm volatile("s_waitcnt vmcnt(10)" ::: "memory");
        else if (ks == NK - 2) asm volatile("s_waitcnt vmcnt(5)" ::: "memory");
        else                   asm volatile("s_waitcnt vmcnt(0)" ::: "memory");
        __builtin_amdgcn_s_barrier();

        const char* Xs = smem + (ks % 3) * 40960;
        const char* Ws = Xs + 8192;
        bf16x8 a[4], b[8];
#pragma unroll
        for (int fm = 0; fm < 4; ++fm) {
            int r = wm * 64 + fm * 16 + ln15;
            a[fm] = *(const bf16x8*)(Xs + r * 64 + ((lg ^ ((r >> 1) & 3)) * 16));
        }
#pragma unroll
        for (int fn = 0; fn < 8; ++fn) {
            int r = wn * 128 + fn * 16 + ln15;
            b[fn] = *(const bf16x8*)(Ws + r * 64 + ((lg ^ ((r >> 1) & 3)) * 16));
        }
        __builtin_amdgcn_s_setprio(1);
#pragma unroll
        for (int fm = 0; fm < 4; ++fm)
#pragma unroll
            for (int fn = 0; fn < 8; ++fn)
                acc[fm][fn] = __builtin_amdgcn_mfma_f32_16x16x32_bf16(a[fm], b[fn], acc[fm][fn], 0, 0, 0);
        __builtin_amdgcn_s_setprio(0);

        // all this wave's LDS reads complete before signaling buffer-free
        asm volatile("s_waitcnt lgkmcnt(0)" ::: "memory");
        __builtin_amdgcn_sched_barrier(0);
        __builtin_amdgcn_s_barrier();
        __builtin_amdgcn_sched_barrier(0);
        if (ks + 3 < NK) stage(ks + 3);
    }

    // ---------------- epilogue (reuses buf0 region of LDS) ----------------
    float* lnred_s = (float*)smem;            // [128][4]
    float* lnred_q = (float*)(smem + 2048);   // [128][4]
    float* lnmv    = (float*)(smem + 4096);   // [128][2]
    float* csred   = (float*)(smem + 5120);   // [2][512]

    // per-lane column constants (8 cols: wn*128 + fn*16 + ln15)
    const int cbase = wn * 128 + ln15;
    float cv[8], gv[8], bv[8];
#pragma unroll
    for (int fn = 0; fn < 8; ++fn) {
        int col = cbase + fn * 16;
        cv[fn] = cvec[col]; gv[fn] = gvec[col]; bv[fn] = bvec[col];
    }

    // add the broadcast c-vector (fp32-exact common term)
#pragma unroll
    for (int fm = 0; fm < 4; ++fm)
#pragma unroll
        for (int fn = 0; fn < 8; ++fn) acc[fm][fn] += cv[fn];

    // per-row sum / sumsq over this wave's 128 cols (shfl tree within 16-lane group)
    float rs[16], rq[16];
#pragma unroll
    for (int fm = 0; fm < 4; ++fm)
#pragma unroll
        for (int j = 0; j < 4; ++j) {
            float s = 0.f, q = 0.f;
#pragma unroll
            for (int fn = 0; fn < 8; ++fn) {
                float x = acc[fm][fn][j];
                s += x; q += x * x;
            }
            rs[fm * 4 + j] = s; rq[fm * 4 + j] = q;
        }
#pragma unroll
    for (int m = 1; m < 16; m <<= 1)
#pragma unroll
        for (int i = 0; i < 16; ++i) {
            rs[i] += __shfl_xor(rs[i], m);
            rq[i] += __shfl_xor(rq[i], m);
        }
    if (ln15 == 0) {
#pragma unroll
        for (int fm = 0; fm < 4; ++fm)
#pragma unroll
            for (int j = 0; j < 4; ++j) {
                int row = wm * 64 + fm * 16 + lg * 4 + j;
                lnred_s[row * 4 + wn] = rs[fm * 4 + j];
                lnred_q[row * 4 + wn] = rq[fm * 4 + j];
            }
    }
    __syncthreads();
    if (t < 128) {
        float s = lnred_s[t * 4] + lnred_s[t * 4 + 1] + lnred_s[t * 4 + 2] + lnred_s[t * 4 + 3];
        float q = lnred_q[t * 4] + lnred_q[t * 4 + 1] + lnred_q[t * 4 + 2] + lnred_q[t * 4 + 3];
        float mu = s * (1.0f / 512.0f);
        float var = q * (1.0f / 512.0f) - mu * mu;
        lnmv[t * 2] = mu;
        lnmv[t * 2 + 1] = rsqrtf(var + EPSV);
    }
    __syncthreads();

    // normalize + relu + (store bf16 packed) ; invalid rows forced to 0 (masked)
#pragma unroll
    for (int fm = 0; fm < 4; ++fm)
#pragma unroll
        for (int j = 0; j < 4; ++j) {
            int rloc = wm * 64 + fm * 16 + lg * 4 + j;
            long rglob = row0 + rloc;
            bool ok = rglob < NPTS;
            float mu = lnmv[rloc * 2], rstd = lnmv[rloc * 2 + 1];
#pragma unroll
            for (int fn = 0; fn < 8; ++fn) {
                float y = fmaxf((acc[fm][fn][j] - mu) * rstd * gv[fn] + bv[fn], 0.0f);
                acc[fm][fn][j] = ok ? y : 0.0f;
            }
            if (STORE && ok) {
#pragma unroll
                for (int fn = 0; fn < 8; ++fn) {
                    int kt = wn * 4 + (fn >> 1);
                    Hout[((long)kt * NPTS_PAD + rglob) * 32 + (fn & 1) * 16 + ln15] =
                        (bf16)acc[fm][fn][j];
                }
            }
        }

    // column partials over the block's 128 rows (sum or max)
    float cp[8];
#pragma unroll
    for (int fn = 0; fn < 8; ++fn) {
        float p = 0.f;
#pragma unroll
        for (int fm = 0; fm < 4; ++fm)
#pragma unroll
            for (int j = 0; j < 4; ++j) {
                float v = acc[fm][fn][j];
                p = (REDOP == 0) ? (p + v) : fmaxf(p, v);
            }
        cp[fn] = p;
    }
#pragma unroll
    for (int m = 16; m < 64; m <<= 1)
#pragma unroll
        for (int fn = 0; fn < 8; ++fn) {
            float o = __shfl_xor(cp[fn], m);
            cp[fn] = (REDOP == 0) ? (cp[fn] + o) : fmaxf(cp[fn], o);
        }
    if (lg == 0) {
#pragma unroll
        for (int fn = 0; fn < 8; ++fn)
            csred[wm * 512 + wn * 128 + fn * 16 + ln15] = cp[fn];
    }
    __syncthreads();
    {
        float a0 = csred[t], a1 = csred[512 + t];
        red_out[(long)blockIdx.x * 512 + t] = (REDOP == 0) ? (a0 + a1) : fmaxf(a0, a1);
    }
}

extern "C" void kernel_launch(void* const* d_in, const int* in_sizes, int n_in,
                              void* d_out, int out_size, void* d_ws, size_t ws_size,
                              hipStream_t stream) {
    const float* in_set = (const float*)d_in[0];
    const float* A0 = (const float*)d_in[1];
    const float* B0 = (const float*)d_in[2];
    const float* A1 = (const float*)d_in[3];
    const float* B1 = (const float*)d_in[4];
    const float* A2 = (const float*)d_in[5];
    const float* B2 = (const float*)d_in[6];
    const float* ga = (const float*)d_in[7];
    const float* be = (const float*)d_in[8];
    const float* ow = (const float*)d_in[9];
    const float* ob = (const float*)d_in[10];
    float* outp = (float*)d_out;
    char* ws = (char*)d_ws;

    bf16* in_bf = (bf16*)(ws + OFF_INBF);
    bf16* W0 = (bf16*)(ws + OFF_W0);
    bf16* W1 = (bf16*)(ws + OFF_W1);
    bf16* W2 = (bf16*)(ws + OFF_W2);
    float* c0 = (float*)(ws + OFF_C0);
    float* c1 = (float*)(ws + OFF_C1);
    float* c2 = (float*)(ws + OFF_C2);
    float* parts = (float*)(ws + OFF_PARTS);
    float* parts2 = (float*)(ws + OFF_PARTS2);
    float* parts3 = (float*)(ws + OFF_PARTS3);
    bf16* h1 = (bf16*)(ws + OFF_H1);
    bf16* h2 = (bf16*)(ws + OFF_H2);

    const int nblk = (NPTS + 127) / 128;  // 782

    cvt_pack_kernel<<<2048, 256, 0, stream>>>(in_set, in_bf);
    wdiff_pack_kernel<<<8, 256, 0, stream>>>(A0, B0, W0, 128);
    wdiff_pack_kernel<<<32, 256, 0, stream>>>(A1, B1, W1, 512);
    wdiff_pack_kernel<<<32, 256, 0, stream>>>(A2, B2, W2, 512);

    // c0 = colsum(in_set) @ B0^T  (all fp32 — the numerically critical path), wide+shallow
    colsum_in_kernel<<<512, 256, 0, stream>>>(in_set, parts);                       // [512][128]
    part_reduceW_kernel<<<64, 128, 0, stream>>>(parts, 512, 128, 0, parts2);        // [64][128]
    part_reduceW_kernel<<<8, 128, 0, stream>>>(parts2, 64, 128, 0, parts3);         // [8][128]
    gemv_fold_kernel<<<512, 64, 0, stream>>>(parts3, 128, B0, nullptr, 0, c0);

    layer_kernel<128, true, 0><<<nblk, 512, 0, stream>>>(in_bf, W0, c0, ga, be, h1, parts);
    part_reduceW_kernel<<<64, 512, 0, stream>>>(parts, nblk, 512, 0, parts2);
    part_reduceW_kernel<<<8, 512, 0, stream>>>(parts2, 64, 512, 0, parts3);
    gemv_fold_kernel<<<512, 64, 0, stream>>>(parts3, 512, B1, nullptr, 0, c1);

    layer_kernel<512, true, 0><<<nblk, 512, 0, stream>>>(h1, W1, c1, ga, be, h2, parts);
    part_reduceW_kernel<<<64, 512, 0, stream>>>(parts, nblk, 512, 0, parts2);
    part_reduceW_kernel<<<8, 512, 0, stream>>>(parts2, 64, 512, 0, parts3);
    gemv_fold_kernel<<<512, 64, 0, stream>>>(parts3, 512, B2, nullptr, 0, c2);

    // layer 2: no h3 store; fused column-max partials; final = (max-fold) @ ow^T + ob
    layer_kernel<512, false, 1><<<nblk, 512, 0, stream>>>(h2, W2, c2, ga, be, nullptr, parts);
    part_reduceW_kernel<<<64, 512, 0, stream>>>(parts, nblk, 512, 1, parts2);
    part_reduceW_kernel<<<8, 512, 0, stream>>>(parts2, 64, 512, 1, parts3);
    gemv_fold_kernel<<<256, 64, 0, stream>>>(parts3, 512, ow, ob, 1, outp);
}

// Round 6
// 346.440 us; speedup vs baseline: 1.0243x; 1.0241x over previous
//
#include <hip/hip_runtime.h>
#include <hip/hip_bf16.h>

#define NPTS 100000
#define NPTS_PAD 100096
#define DHID 512
#define EPSV 1e-5f

typedef __bf16 bf16;
typedef __attribute__((ext_vector_type(8))) __bf16 bf16x8;
typedef __attribute__((ext_vector_type(4))) __bf16 bf16x4;
typedef __attribute__((ext_vector_type(4))) float f32x4;

// ---- workspace layout (bytes) ----
// All operands k-tiled: Xp/Hp = [kt][NPTS_PAD][32] bf16, Wp = [kt][512][32] bf16
#define OFF_INBF   0UL            // 4*100096*32*2  = 25,624,576
#define OFF_W0     25624576UL     // 4*512*32*2     = 131,072
#define OFF_W1     25755648UL     // 16*512*32*2    = 524,288
#define OFF_W2     26279936UL     // 524,288
#define OFF_C0     26804224UL     // 512*4
#define OFF_C1     26806272UL
#define OFF_C2     26808320UL
#define OFF_PARTS  26810368UL     // 1563*512*4 = 3,201,024
#define OFF_PARTS2 30011392UL     // 64*512*4
#define OFF_PARTS3 30142464UL     // 8*512*4
#define OFF_H1     30158848UL     // 16*100096*32*2 = 102,498,304
#define OFF_H2     132657152UL    // 102,498,304  (end 235,155,456)

typedef const __attribute__((address_space(1))) unsigned int* gp_t;
typedef __attribute__((address_space(3))) unsigned int* lp_t;

__device__ __forceinline__ void async_copy16(const void* g, void* l) {
    __builtin_amdgcn_global_load_lds((gp_t)g, (lp_t)l, 16, 0, 0);
}

// ---------- prep: fp32 [NPTS][128] -> packed bf16 [4][NPTS_PAD][32] ----------
__global__ __launch_bounds__(256) void cvt_pack_kernel(const float* __restrict__ in,
                                                       bf16* __restrict__ out) {
    long total = (long)NPTS * 4;
    long stride = (long)gridDim.x * blockDim.x;
    for (long idx = (long)blockIdx.x * blockDim.x + threadIdx.x; idx < total; idx += stride) {
        int kt = (int)(idx / NPTS);
        long r = idx - (long)kt * NPTS;
        const float4* src = (const float4*)(in + r * 128 + kt * 32);
        bf16* dst = out + ((long)kt * NPTS_PAD + r) * 32;
#pragma unroll
        for (int j = 0; j < 8; ++j) {
            float4 v = src[j];
            bf16x4 o = { (bf16)v.x, (bf16)v.y, (bf16)v.z, (bf16)v.w };
            *(bf16x4*)(dst + j * 4) = o;
        }
    }
}

// ---------- prep: packed W = bf16(A - B), [NK][512][32] ----------
__global__ __launch_bounds__(256) void wdiff_pack_kernel(const float* __restrict__ A,
                                                         const float* __restrict__ B,
                                                         bf16* __restrict__ Wp, int KD) {
    int NK = KD / 32;
    int total = 512 * NK;
    int idx = blockIdx.x * blockDim.x + threadIdx.x;
    if (idx >= total) return;
    int kt = idx / 512, row = idx - kt * 512;
    const float4* sa = (const float4*)(A + (long)row * KD + kt * 32);
    const float4* sb = (const float4*)(B + (long)row * KD + kt * 32);
    bf16* dst = Wp + ((long)kt * 512 + row) * 32;
#pragma unroll
    for (int j = 0; j < 8; ++j) {
        float4 a = sa[j], b = sb[j];
        bf16x4 o = { (bf16)(a.x - b.x), (bf16)(a.y - b.y), (bf16)(a.z - b.z), (bf16)(a.w - b.w) };
        *(bf16x4*)(dst + j * 4) = o;
    }
}

// ---------- colsum of in_set (fp32, deterministic 2-stage) ----------
__global__ __launch_bounds__(256) void colsum_in_kernel(const float* __restrict__ in,
                                                        float* __restrict__ parts) {
    __shared__ float sh[256];
    int t = threadIdx.x, blk = blockIdx.x;
    int c = t & 127, half = t >> 7;
    long rbeg = (long)blk * 196 + half;
    long rend = (long)(blk + 1) * 196; if (rend > NPTS) rend = NPTS;
    float s = 0.f;
    for (long r = rbeg; r < rend; r += 2) s += in[r * 128 + c];
    sh[t] = s;
    __syncthreads();
    if (t < 128) parts[blk * 128 + t] = sh[t] + sh[t + 128];
}

// ---------- generic partial reduce: parts[nparts][width] -> out[grid][width] ----------
__global__ void part_reduceW_kernel(const float* __restrict__ parts, int nparts, int width,
                                    int op, float* __restrict__ out) {
    int g = blockIdx.x, t = threadIdx.x;
    int chunk = (nparts + gridDim.x - 1) / gridDim.x;
    int b0 = g * chunk, b1 = b0 + chunk; if (b1 > nparts) b1 = nparts;
    float s = 0.f;  // identity 0 valid for max too: values are post-relu >= 0
    for (int b = b0; b < b1; ++b) {
        float v = parts[(long)b * width + t];
        s = (op == 0) ? (s + v) : fmaxf(s, v);
    }
    out[(long)g * width + t] = s;
}

// ---------- fold 8 partial rows + GEMV: out[j] = (fold_g p3[g][:]) . Bm[j][:] + bias ----------
__global__ __launch_bounds__(64) void gemv_fold_kernel(const float* __restrict__ p3, int dsum,
                                                       const float* __restrict__ Bm,
                                                       const float* __restrict__ bias, int op,
                                                       float* __restrict__ out) {
    int j = blockIdx.x, t = threadIdx.x;
    float acc = 0.f;
    for (int d = t; d < dsum; d += 64) {
        float s = 0.f;
#pragma unroll
        for (int g = 0; g < 8; ++g) {
            float v = p3[(long)g * dsum + d];
            s = (op == 0) ? (s + v) : fmaxf(s, v);
        }
        acc += s * Bm[(long)j * dsum + d];
    }
#pragma unroll
    for (int m = 32; m >= 1; m >>= 1) acc += __shfl_down(acc, m);
    if (t == 0) out[j] = acc + (bias ? bias[j] : 0.0f);
}

// ---------- fused layer: C = X@W^T (bf16 MFMA) + c ; LN ; relu ; store bf16 ; col-red ----------
// BM=128, BN=512, BK=32, 512 threads = 8 waves (2Mx4N). 8-PHASE interleave (T3+T4, m201
// template adapted): per kstep, 4 phases x {ds_read subtile || issue 1-2 global_load_lds
// (tile ks+2, tribuf) ; s_barrier ; setprio(1) ; 8 MFMA ; setprio(0) ; s_barrier}.
// Loads span 8 barrier intervals; counted vmcnt(5) once per kstep (never 0 mid-loop).
// ds_read<-MFMA waits left to compiler (reads compiler-visible); manual vmcnt covers the
// invisible gload_lds -> ds_read dependency. Tribuf 3x40KB = 120KB, 1 block/CU.
template<int KD, bool STORE, int REDOP>  // REDOP 0=sum, 1=max
__global__ __launch_bounds__(512, 2)
void layer_kernel(const bf16* __restrict__ Xp, const bf16* __restrict__ Wp,
                  const float* __restrict__ cvec, const float* __restrict__ gvec,
                  const float* __restrict__ bvec, bf16* __restrict__ Hout,
                  float* __restrict__ red_out) {
    static_assert(KD % 32 == 0, "");
    constexpr int NK = KD / 32;
    // per buffer: Xs[128][32] bf16 = 8192 B, Ws[512][32] bf16 = 32768 B
    __shared__ __align__(128) char smem[3 * 40960];

    const int t = threadIdx.x;
    const int lane = t & 63;
    const int wid = t >> 6;          // 0..7
    const int wm = wid >> 2;         // 0..1  (M half: 64 rows)
    const int wn = wid & 3;          // 0..3  (N quarter: 128 cols)
    const int ln15 = lane & 15;
    const int lg = lane >> 4;        // 0..3
    const long row0 = (long)blockIdx.x * 128;

    f32x4 acc[4][8];
#pragma unroll
    for (int i = 0; i < 4; ++i)
#pragma unroll
        for (int j = 0; j < 8; ++j) acc[i][j] = (f32x4){0.f, 0.f, 0.f, 0.f};

    // ---- staging geometry (all-contiguous sources) ----
    const int l4 = lane >> 2;                       // row-within-16
    const int soff = ((lane & 3) ^ ((lane >> 3) & 3)) * 16;   // permuted 16B slot in row's 64B
    const char* Xbase = (const char*)Xp + (row0 + wid * 16 + l4) * 64 + soff;
    const char* Wbase = (const char*)Wp + (wid * 4096 + l4 * 64) + soff;

    auto stage_x = [&](int ks) {
        char* Xs = smem + (ks % 3) * 40960;
        async_copy16(Xbase + (long)ks * (NPTS_PAD * 64), Xs + wid * 1024 + lane * 16);
    };
    auto stage_w = [&](int ks, int q) {
        char* Ws = smem + (ks % 3) * 40960 + 8192;
        async_copy16(Wbase + ks * 32768 + q * 1024, Ws + wid * 4096 + q * 1024 + lane * 16);
    };

    // prologue: tiles 0,1 fully staged (10 outstanding per wave)
    stage_x(0);
#pragma unroll
    for (int q = 0; q < 4; ++q) stage_w(0, q);
    stage_x(1);
#pragma unroll
    for (int q = 0; q < 4; ++q) stage_w(1, q);
    asm volatile("s_waitcnt vmcnt(5)" ::: "memory");   // tile 0 ready; tile 1 in flight
    __builtin_amdgcn_s_barrier();
    __builtin_amdgcn_sched_barrier(0);

#define RD_A(fm) (*(const bf16x8*)(Xs + (wm * 64 + (fm) * 16 + ln15) * 64 + \
                    ((lg ^ (((wm * 64 + (fm) * 16 + ln15) >> 1) & 3)) * 16)))
#define RD_B(fn) (*(const bf16x8*)(Ws + (wn * 128 + (fn) * 16 + ln15) * 64 + \
                    ((lg ^ (((wn * 128 + (fn) * 16 + ln15) >> 1) & 3)) * 16)))
#define MFMA8(FN0, FN1)                                                                   \
    __builtin_amdgcn_s_setprio(1);                                                        \
    _Pragma("unroll")                                                                     \
    for (int fm = 0; fm < 4; ++fm) {                                                      \
        acc[fm][FN0] = __builtin_amdgcn_mfma_f32_16x16x32_bf16(a[fm], b[FN0], acc[fm][FN0], 0, 0, 0); \
        acc[fm][FN1] = __builtin_amdgcn_mfma_f32_16x16x32_bf16(a[fm], b[FN1], acc[fm][FN1], 0, 0, 0); \
    }                                                                                     \
    __builtin_amdgcn_s_setprio(0);

#pragma unroll
    for (int ks = 0; ks < NK; ++ks) {
        const char* Xs = smem + (ks % 3) * 40960;
        const char* Ws = Xs + 8192;
        const int sn = ks + 2;            // tile staged during this kstep
        bf16x8 a[4], b[8];

        // ---- phase 0: a[0..3], b[0..1] ; stage x + w0 ; 8 MFMA (fn 0,1) ----
        a[0] = RD_A(0); a[1] = RD_A(1); a[2] = RD_A(2); a[3] = RD_A(3);
        b[0] = RD_B(0); b[1] = RD_B(1);
        if (sn < NK) { stage_x(sn); stage_w(sn, 0); }
        __builtin_amdgcn_s_barrier();
        __builtin_amdgcn_sched_barrier(0);
        MFMA8(0, 1)
        __builtin_amdgcn_sched_barrier(0);
        __builtin_amdgcn_s_barrier();
        __builtin_amdgcn_sched_barrier(0);

        // ---- phase 1: b[2..3] ; stage w1 ; 8 MFMA (fn 2,3) ----
        b[2] = RD_B(2); b[3] = RD_B(3);
        if (sn < NK) stage_w(sn, 1);
        __builtin_amdgcn_s_barrier();
        __builtin_amdgcn_sched_barrier(0);
        MFMA8(2, 3)
        __builtin_amdgcn_sched_barrier(0);
        __builtin_amdgcn_s_barrier();
        __builtin_amdgcn_sched_barrier(0);

        // ---- phase 2: b[4..5] ; stage w2 ; 8 MFMA (fn 4,5) ----
        b[4] = RD_B(4); b[5] = RD_B(5);
        if (sn < NK) stage_w(sn, 2);
        __builtin_amdgcn_s_barrier();
        __builtin_amdgcn_sched_barrier(0);
        MFMA8(4, 5)
        __builtin_amdgcn_sched_barrier(0);
        __builtin_amdgcn_s_barrier();
        __builtin_amdgcn_sched_barrier(0);

        // ---- phase 3: b[6..7] ; stage w3 ; 8 MFMA (fn 6,7) ; kstep-boundary wait ----
        b[6] = RD_B(6); b[7] = RD_B(7);
        if (sn < NK) stage_w(sn, 3);
        __builtin_amdgcn_s_barrier();
        __builtin_amdgcn_sched_barrier(0);
        MFMA8(6, 7)
        __builtin_amdgcn_sched_barrier(0);
        // next kstep's buffer must be resident before any wave's P0 ds_read
        if (ks + 1 < NK) {
            if (sn < NK) asm volatile("s_waitcnt vmcnt(5)" ::: "memory");
            else         asm volatile("s_waitcnt vmcnt(0)" ::: "memory");
        }
        __builtin_amdgcn_s_barrier();
        __builtin_amdgcn_sched_barrier(0);
    }
#undef RD_A
#undef RD_B
#undef MFMA8

    // ---------------- epilogue (reuses buf0 region of LDS) ----------------
    float* lnred_s = (float*)smem;            // [128][4]
    float* lnred_q = (float*)(smem + 2048);   // [128][4]
    float* lnmv    = (float*)(smem + 4096);   // [128][2]
    float* csred   = (float*)(smem + 5120);   // [2][512]

    // per-lane column constants (8 cols: wn*128 + fn*16 + ln15)
    const int cbase = wn * 128 + ln15;
    float cv[8], gv[8], bv[8];
#pragma unroll
    for (int fn = 0; fn < 8; ++fn) {
        int col = cbase + fn * 16;
        cv[fn] = cvec[col]; gv[fn] = gvec[col]; bv[fn] = bvec[col];
    }

    // add the broadcast c-vector (fp32-exact common term)
#pragma unroll
    for (int fm = 0; fm < 4; ++fm)
#pragma unroll
        for (int fn = 0; fn < 8; ++fn) acc[fm][fn] += cv[fn];

    // per-row sum / sumsq over this wave's 128 cols (shfl tree within 16-lane group)
    float rs[16], rq[16];
#pragma unroll
    for (int fm = 0; fm < 4; ++fm)
#pragma unroll
        for (int j = 0; j < 4; ++j) {
            float s = 0.f, q = 0.f;
#pragma unroll
            for (int fn = 0; fn < 8; ++fn) {
                float x = acc[fm][fn][j];
                s += x; q += x * x;
            }
            rs[fm * 4 + j] = s; rq[fm * 4 + j] = q;
        }
#pragma unroll
    for (int m = 1; m < 16; m <<= 1)
#pragma unroll
        for (int i = 0; i < 16; ++i) {
            rs[i] += __shfl_xor(rs[i], m);
            rq[i] += __shfl_xor(rq[i], m);
        }
    if (ln15 == 0) {
#pragma unroll
        for (int fm = 0; fm < 4; ++fm)
#pragma unroll
            for (int j = 0; j < 4; ++j) {
                int row = wm * 64 + fm * 16 + lg * 4 + j;
                lnred_s[row * 4 + wn] = rs[fm * 4 + j];
                lnred_q[row * 4 + wn] = rq[fm * 4 + j];
            }
    }
    __syncthreads();
    if (t < 128) {
        float s = lnred_s[t * 4] + lnred_s[t * 4 + 1] + lnred_s[t * 4 + 2] + lnred_s[t * 4 + 3];
        float q = lnred_q[t * 4] + lnred_q[t * 4 + 1] + lnred_q[t * 4 + 2] + lnred_q[t * 4 + 3];
        float mu = s * (1.0f / 512.0f);
        float var = q * (1.0f / 512.0f) - mu * mu;
        lnmv[t * 2] = mu;
        lnmv[t * 2 + 1] = rsqrtf(var + EPSV);
    }
    __syncthreads();

    // normalize + relu + (store bf16 packed) ; invalid rows forced to 0 (masked)
#pragma unroll
    for (int fm = 0; fm < 4; ++fm)
#pragma unroll
        for (int j = 0; j < 4; ++j) {
            int rloc = wm * 64 + fm * 16 + lg * 4 + j;
            long rglob = row0 + rloc;
            bool ok = rglob < NPTS;
            float mu = lnmv[rloc * 2], rstd = lnmv[rloc * 2 + 1];
#pragma unroll
            for (int fn = 0; fn < 8; ++fn) {
                float y = fmaxf((acc[fm][fn][j] - mu) * rstd * gv[fn] + bv[fn], 0.0f);
                acc[fm][fn][j] = ok ? y : 0.0f;
            }
            if (STORE && ok) {
#pragma unroll
                for (int fn = 0; fn < 8; ++fn) {
                    int kt = wn * 4 + (fn >> 1);
                    Hout[((long)kt * NPTS_PAD + rglob) * 32 + (fn & 1) * 16 + ln15] =
                        (bf16)acc[fm][fn][j];
                }
            }
        }

    // column partials over the block's 128 rows (sum or max)
    float cp[8];
#pragma unroll
    for (int fn = 0; fn < 8; ++fn) {
        float p = 0.f;
#pragma unroll
        for (int fm = 0; fm < 4; ++fm)
#pragma unroll
            for (int j = 0; j < 4; ++j) {
                float v = acc[fm][fn][j];
                p = (REDOP == 0) ? (p + v) : fmaxf(p, v);
            }
        cp[fn] = p;
    }
#pragma unroll
    for (int m = 16; m < 64; m <<= 1)
#pragma unroll
        for (int fn = 0; fn < 8; ++fn) {
            float o = __shfl_xor(cp[fn], m);
            cp[fn] = (REDOP == 0) ? (cp[fn] + o) : fmaxf(cp[fn], o);
        }
    if (lg == 0) {
#pragma unroll
        for (int fn = 0; fn < 8; ++fn)
            csred[wm * 512 + wn * 128 + fn * 16 + ln15] = cp[fn];
    }
    __syncthreads();
    {
        float a0 = csred[t], a1 = csred[512 + t];
        red_out[(long)blockIdx.x * 512 + t] = (REDOP == 0) ? (a0 + a1) : fmaxf(a0, a1);
    }
}

extern "C" void kernel_launch(void* const* d_in, const int* in_sizes, int n_in,
                              void* d_out, int out_size, void* d_ws, size_t ws_size,
                              hipStream_t stream) {
    const float* in_set = (const float*)d_in[0];
    const float* A0 = (const float*)d_in[1];
    const float* B0 = (const float*)d_in[2];
    const float* A1 = (const float*)d_in[3];
    const float* B1 = (const float*)d_in[4];
    const float* A2 = (const float*)d_in[5];
    const float* B2 = (const float*)d_in[6];
    const float* ga = (const float*)d_in[7];
    const float* be = (const float*)d_in[8];
    const float* ow = (const float*)d_in[9];
    const float* ob = (const float*)d_in[10];
    float* outp = (float*)d_out;
    char* ws = (char*)d_ws;

    bf16* in_bf = (bf16*)(ws + OFF_INBF);
    bf16* W0 = (bf16*)(ws + OFF_W0);
    bf16* W1 = (bf16*)(ws + OFF_W1);
    bf16* W2 = (bf16*)(ws + OFF_W2);
    float* c0 = (float*)(ws + OFF_C0);
    float* c1 = (float*)(ws + OFF_C1);
    float* c2 = (float*)(ws + OFF_C2);
    float* parts = (float*)(ws + OFF_PARTS);
    float* parts2 = (float*)(ws + OFF_PARTS2);
    float* parts3 = (float*)(ws + OFF_PARTS3);
    bf16* h1 = (bf16*)(ws + OFF_H1);
    bf16* h2 = (bf16*)(ws + OFF_H2);

    const int nblk = (NPTS + 127) / 128;  // 782

    cvt_pack_kernel<<<2048, 256, 0, stream>>>(in_set, in_bf);
    wdiff_pack_kernel<<<8, 256, 0, stream>>>(A0, B0, W0, 128);
    wdiff_pack_kernel<<<32, 256, 0, stream>>>(A1, B1, W1, 512);
    wdiff_pack_kernel<<<32, 256, 0, stream>>>(A2, B2, W2, 512);

    // c0 = colsum(in_set) @ B0^T  (all fp32 — the numerically critical path), wide+shallow
    colsum_in_kernel<<<512, 256, 0, stream>>>(in_set, parts);                       // [512][128]
    part_reduceW_kernel<<<64, 128, 0, stream>>>(parts, 512, 128, 0, parts2);        // [64][128]
    part_reduceW_kernel<<<8, 128, 0, stream>>>(parts2, 64, 128, 0, parts3);         // [8][128]
    gemv_fold_kernel<<<512, 64, 0, stream>>>(parts3, 128, B0, nullptr, 0, c0);

    layer_kernel<128, true, 0><<<nblk, 512, 0, stream>>>(in_bf, W0, c0, ga, be, h1, parts);
    part_reduceW_kernel<<<64, 512, 0, stream>>>(parts, nblk, 512, 0, parts2);
    part_reduceW_kernel<<<8, 512, 0, stream>>>(parts2, 64, 512, 0, parts3);
    gemv_fold_kernel<<<512, 64, 0, stream>>>(parts3, 512, B1, nullptr, 0, c1);

    layer_kernel<512, true, 0><<<nblk, 512, 0, stream>>>(h1, W1, c1, ga, be, h2, parts);
    part_reduceW_kernel<<<64, 512, 0, stream>>>(parts, nblk, 512, 0, parts2);
    part_reduceW_kernel<<<8, 512, 0, stream>>>(parts2, 64, 512, 0, parts3);
    gemv_fold_kernel<<<512, 64, 0, stream>>>(parts3, 512, B2, nullptr, 0, c2);

    // layer 2: no h3 store; fused column-max partials; final = (max-fold) @ ow^T + ob
    layer_kernel<512, false, 1><<<nblk, 512, 0, stream>>>(h2, W2, c2, ga, be, nullptr, parts);
    part_reduceW_kernel<<<64, 512, 0, stream>>>(parts, nblk, 512, 1, parts2);
    part_reduceW_kernel<<<8, 512, 0, stream>>>(parts2, 64, 512, 1, parts3);
    gemv_fold_kernel<<<256, 64, 0, stream>>>(parts3, 512, ow, ob, 1, outp);
}

// Round 7
// 338.796 us; speedup vs baseline: 1.0474x; 1.0226x over previous
//
#include <hip/hip_runtime.h>
#include <hip/hip_bf16.h>

#define NPTS 100000
#define NPTS_PAD 100096
#define DHID 512
#define EPSV 1e-5f

typedef __attribute__((ext_vector_type(4))) float f32x4;

// ---- workspace layout (bytes) ----
// Operands k-tiled in fp8 e4m3: Xp/Hp = [KD/64][NPTS_PAD][64] bytes, Wp = [KD/64][512][64]
#define OFF_INBF   0UL            // 2*100096*64 = 12,812,288
#define OFF_W0     12812288UL     // 2*512*64    = 65,536
#define OFF_W1     12877824UL     // 8*512*64    = 262,144
#define OFF_W2     13139968UL     // 262,144
#define OFF_C0     13402112UL     // 512*4 (pad to 2048)
#define OFF_C1     13404160UL
#define OFF_C2     13406208UL
#define OFF_PARTS  13408256UL     // 1563*512*4 = 3,201,024
#define OFF_PARTS2 16609280UL     // 64*512*4 = 131,072
#define OFF_PARTS3 16740352UL     // 8*512*4 = 16,384
#define OFF_H1     16756736UL     // 8*100096*64 = 51,249,152
#define OFF_H2     68005888UL     // 51,249,152  (end 119,255,040)

typedef const __attribute__((address_space(1))) unsigned int* gp_t;
typedef __attribute__((address_space(3))) unsigned int* lp_t;

__device__ __forceinline__ void async_copy16(const void* g, void* l) {
    __builtin_amdgcn_global_load_lds((gp_t)g, (lp_t)l, 16, 0, 0);
}

// pack 4 floats -> 4 fp8 e4m3 bytes (RNE, v_cvt_pk_fp8_f32)
__device__ __forceinline__ unsigned pack4_fp8(float a, float b, float c, float d) {
    unsigned v = (unsigned)__builtin_amdgcn_cvt_pk_fp8_f32(a, b, 0, false);
    v = (unsigned)__builtin_amdgcn_cvt_pk_fp8_f32(c, d, (int)v, true);
    return v;
}

// ---------- prep: fp32 [NPTS][128] -> fp8 [2][NPTS_PAD][64] ----------
__global__ __launch_bounds__(256) void cvt_pack_kernel(const float* __restrict__ in,
                                                       unsigned char* __restrict__ out) {
    long total = (long)NPTS * 2;
    long stride = (long)gridDim.x * blockDim.x;
    for (long idx = (long)blockIdx.x * blockDim.x + threadIdx.x; idx < total; idx += stride) {
        int kt = (int)(idx / NPTS);
        long r = idx - (long)kt * NPTS;
        const float* src = in + r * 128 + kt * 64;
        unsigned dw[16];
#pragma unroll
        for (int j = 0; j < 16; ++j)
            dw[j] = pack4_fp8(src[4 * j], src[4 * j + 1], src[4 * j + 2], src[4 * j + 3]);
        uint4* dst = (uint4*)(out + ((long)kt * NPTS_PAD + r) * 64);
#pragma unroll
        for (int j = 0; j < 4; ++j)
            dst[j] = make_uint4(dw[4 * j], dw[4 * j + 1], dw[4 * j + 2], dw[4 * j + 3]);
    }
}

// ---------- prep: packed W = fp8(A - B), [KD/64][512][64] ----------
__global__ __launch_bounds__(256) void wdiff_pack_kernel(const float* __restrict__ A,
                                                         const float* __restrict__ B,
                                                         unsigned char* __restrict__ Wp, int KD) {
    int NKT = KD / 64;
    int total = 512 * NKT;
    int idx = blockIdx.x * blockDim.x + threadIdx.x;
    if (idx >= total) return;
    int kt = idx / 512, row = idx - kt * 512;
    const float* sa = A + (long)row * KD + kt * 64;
    const float* sb = B + (long)row * KD + kt * 64;
    unsigned dw[16];
#pragma unroll
    for (int j = 0; j < 16; ++j)
        dw[j] = pack4_fp8(sa[4 * j] - sb[4 * j], sa[4 * j + 1] - sb[4 * j + 1],
                          sa[4 * j + 2] - sb[4 * j + 2], sa[4 * j + 3] - sb[4 * j + 3]);
    uint4* dst = (uint4*)(Wp + ((long)kt * 512 + row) * 64);
#pragma unroll
    for (int j = 0; j < 4; ++j)
        dst[j] = make_uint4(dw[4 * j], dw[4 * j + 1], dw[4 * j + 2], dw[4 * j + 3]);
}

// ---------- colsum of in_set (fp32, deterministic 2-stage) ----------
__global__ __launch_bounds__(256) void colsum_in_kernel(const float* __restrict__ in,
                                                        float* __restrict__ parts) {
    __shared__ float sh[256];
    int t = threadIdx.x, blk = blockIdx.x;
    int c = t & 127, half = t >> 7;
    long rbeg = (long)blk * 196 + half;
    long rend = (long)(blk + 1) * 196; if (rend > NPTS) rend = NPTS;
    float s = 0.f;
    for (long r = rbeg; r < rend; r += 2) s += in[r * 128 + c];
    sh[t] = s;
    __syncthreads();
    if (t < 128) parts[blk * 128 + t] = sh[t] + sh[t + 128];
}

// ---------- generic partial reduce: parts[nparts][width] -> out[grid][width] ----------
__global__ void part_reduceW_kernel(const float* __restrict__ parts, int nparts, int width,
                                    int op, float* __restrict__ out) {
    int g = blockIdx.x, t = threadIdx.x;
    int chunk = (nparts + gridDim.x - 1) / gridDim.x;
    int b0 = g * chunk, b1 = b0 + chunk; if (b1 > nparts) b1 = nparts;
    float s = 0.f;  // identity 0 valid for max too: values are post-relu >= 0
    for (int b = b0; b < b1; ++b) {
        float v = parts[(long)b * width + t];
        s = (op == 0) ? (s + v) : fmaxf(s, v);
    }
    out[(long)g * width + t] = s;
}

// ---------- fold 8 partial rows + GEMV: out[j] = (fold_g p3[g][:]) . Bm[j][:] + bias ----------
__global__ __launch_bounds__(64) void gemv_fold_kernel(const float* __restrict__ p3, int dsum,
                                                       const float* __restrict__ Bm,
                                                       const float* __restrict__ bias, int op,
                                                       float* __restrict__ out) {
    int j = blockIdx.x, t = threadIdx.x;
    float acc = 0.f;
    for (int d = t; d < dsum; d += 64) {
        float s = 0.f;
#pragma unroll
        for (int g = 0; g < 8; ++g) {
            float v = p3[(long)g * dsum + d];
            s = (op == 0) ? (s + v) : fmaxf(s, v);
        }
        acc += s * Bm[(long)j * dsum + d];
    }
#pragma unroll
    for (int m = 32; m >= 1; m >>= 1) acc += __shfl_down(acc, m);
    if (t == 0) out[j] = acc + (bias ? bias[j] : 0.0f);
}

// ---------- fused layer (fp8): C = X@W^T (fp8 MFMA) + c ; LN ; relu ; store fp8 ; col-red ----
// BM=128, BN=512, BK=64 (bytes = same 64B rows as the verified bf16 BK=32 layout), 8 waves.
// Per kstep: 40 x global_load_lds (5/wave) stage 40KB; 64 MFMA/wave (2 k-subtiles).
// Tribuf 3x40KB, counted vmcnt ladder 10/5/0 (R5 structure, verified). Staging/byte-geometry
// identical to R5/R6. fp8 halves both staging insts/FLOP and h HBM traffic vs bf16.
template<int KD, bool STORE, int REDOP>  // REDOP 0=sum, 1=max
__global__ __launch_bounds__(512, 2)
void layer_kernel(const unsigned char* __restrict__ Xp, const unsigned char* __restrict__ Wp,
                  const float* __restrict__ cvec, const float* __restrict__ gvec,
                  const float* __restrict__ bvec, unsigned char* __restrict__ Hout,
                  float* __restrict__ red_out) {
    static_assert(KD % 64 == 0, "");
    constexpr int NK = KD / 64;
    // per buffer: Xs[128][64] fp8 = 8192 B, Ws[512][64] fp8 = 32768 B
    __shared__ __align__(128) char smem[3 * 40960];

    const int t = threadIdx.x;
    const int lane = t & 63;
    const int wid = t >> 6;          // 0..7
    const int wm = wid >> 2;         // 0..1  (M half: 64 rows)
    const int wn = wid & 3;          // 0..3  (N quarter: 128 cols)
    const int ln15 = lane & 15;
    const int lg = lane >> 4;        // 0..3
    const long row0 = (long)blockIdx.x * 128;

    f32x4 acc[4][8];
#pragma unroll
    for (int i = 0; i < 4; ++i)
#pragma unroll
        for (int j = 0; j < 8; ++j) acc[i][j] = (f32x4){0.f, 0.f, 0.f, 0.f};

    // ---- staging geometry (byte-identical to verified R5/R6) ----
    const int l4 = lane >> 2;                                 // row-within-16
    const int soff = ((lane & 3) ^ ((lane >> 3) & 3)) * 16;   // permuted 16B slot in row's 64B
    const char* Xbase = (const char*)Xp + (row0 + wid * 16 + l4) * 64 + soff;
    const char* Wbase = (const char*)Wp + (wid * 4096 + l4 * 64) + soff;

    auto stage = [&](int ks) {
        char* Xs = smem + (ks % 3) * 40960;
        char* Ws = Xs + 8192;
        async_copy16(Xbase + (long)ks * (NPTS_PAD * 64), Xs + wid * 1024 + lane * 16);
#pragma unroll
        for (int q = 0; q < 4; ++q)
            async_copy16(Wbase + ks * 32768 + q * 1024,
                         Ws + wid * 4096 + q * 1024 + lane * 16);
    };

    // prologue: up to 3 tiles in flight (15 outstanding per wave)
    stage(0);
    if (NK > 1) stage(1);
    if (NK > 2) stage(2);

    // LDS read: row r, MFMA k-subtile ksub, k-group lg -> global 16B slot g = ksub*2+(lg>>1),
    // stored at slot g ^ ((r>>1)&3), byte offset +(lg&1)*8 within the slot.
#define RD8(BASE, r, ksub) (*(const long*)((BASE) + (r) * 64 + \
        (((((ksub) * 2 + (lg >> 1)) ^ (((r) >> 1) & 3)) * 16) + (lg & 1) * 8)))

#pragma unroll
    for (int ks = 0; ks < NK; ++ks) {
        // wait tile ks only; tiles ks+1, ks+2 stay in flight across the barriers (T4)
        if (ks <= NK - 3)      asm volatile("s_waitcnt vmcnt(10)" ::: "memory");
        else if (ks == NK - 2) asm volatile("s_waitcnt vmcnt(5)" ::: "memory");
        else                   asm volatile("s_waitcnt vmcnt(0)" ::: "memory");
        __builtin_amdgcn_s_barrier();

        const char* Xs = smem + (ks % 3) * 40960;
        const char* Ws = Xs + 8192;
        long a0[4], a1[4], b0[8], b1[8];
#pragma unroll
        for (int fm = 0; fm < 4; ++fm) {
            int r = wm * 64 + fm * 16 + ln15;
            a0[fm] = RD8(Xs, r, 0);
            a1[fm] = RD8(Xs, r, 1);
        }
#pragma unroll
        for (int fn = 0; fn < 8; ++fn) {
            int r = wn * 128 + fn * 16 + ln15;
            b0[fn] = RD8(Ws, r, 0);
            b1[fn] = RD8(Ws, r, 1);
        }
        __builtin_amdgcn_s_setprio(1);
#pragma unroll
        for (int fm = 0; fm < 4; ++fm)
#pragma unroll
            for (int fn = 0; fn < 8; ++fn)
                acc[fm][fn] = __builtin_amdgcn_mfma_f32_16x16x32_fp8_fp8(a0[fm], b0[fn], acc[fm][fn], 0, 0, 0);
#pragma unroll
        for (int fm = 0; fm < 4; ++fm)
#pragma unroll
            for (int fn = 0; fn < 8; ++fn)
                acc[fm][fn] = __builtin_amdgcn_mfma_f32_16x16x32_fp8_fp8(a1[fm], b1[fn], acc[fm][fn], 0, 0, 0);
        __builtin_amdgcn_s_setprio(0);

        // all this wave's LDS reads complete before signaling buffer-free
        asm volatile("s_waitcnt lgkmcnt(0)" ::: "memory");
        __builtin_amdgcn_sched_barrier(0);
        __builtin_amdgcn_s_barrier();
        __builtin_amdgcn_sched_barrier(0);
        if (ks + 3 < NK) stage(ks + 3);
    }
#undef RD8

    // ---------------- epilogue (reuses buf0 region of LDS) ----------------
    float* lnred_s = (float*)smem;            // [128][4]
    float* lnred_q = (float*)(smem + 2048);   // [128][4]
    float* lnmv    = (float*)(smem + 4096);   // [128][2]
    float* csred   = (float*)(smem + 5120);   // [2][512]

    // per-lane column constants (8 cols: wn*128 + fn*16 + ln15)
    const int cbase = wn * 128 + ln15;
    float cv[8], gv[8], bv[8];
#pragma unroll
    for (int fn = 0; fn < 8; ++fn) {
        int col = cbase + fn * 16;
        cv[fn] = cvec[col]; gv[fn] = gvec[col]; bv[fn] = bvec[col];
    }

    // add the broadcast c-vector (fp32-exact common term)
#pragma unroll
    for (int fm = 0; fm < 4; ++fm)
#pragma unroll
        for (int fn = 0; fn < 8; ++fn) acc[fm][fn] += cv[fn];

    // per-row sum / sumsq over this wave's 128 cols (shfl tree within 16-lane group)
    float rs[16], rq[16];
#pragma unroll
    for (int fm = 0; fm < 4; ++fm)
#pragma unroll
        for (int j = 0; j < 4; ++j) {
            float s = 0.f, q = 0.f;
#pragma unroll
            for (int fn = 0; fn < 8; ++fn) {
                float x = acc[fm][fn][j];
                s += x; q += x * x;
            }
            rs[fm * 4 + j] = s; rq[fm * 4 + j] = q;
        }
#pragma unroll
    for (int m = 1; m < 16; m <<= 1)
#pragma unroll
        for (int i = 0; i < 16; ++i) {
            rs[i] += __shfl_xor(rs[i], m);
            rq[i] += __shfl_xor(rq[i], m);
        }
    if (ln15 == 0) {
#pragma unroll
        for (int fm = 0; fm < 4; ++fm)
#pragma unroll
            for (int j = 0; j < 4; ++j) {
                int row = wm * 64 + fm * 16 + lg * 4 + j;
                lnred_s[row * 4 + wn] = rs[fm * 4 + j];
                lnred_q[row * 4 + wn] = rq[fm * 4 + j];
            }
    }
    __syncthreads();
    if (t < 128) {
        float s = lnred_s[t * 4] + lnred_s[t * 4 + 1] + lnred_s[t * 4 + 2] + lnred_s[t * 4 + 3];
        float q = lnred_q[t * 4] + lnred_q[t * 4 + 1] + lnred_q[t * 4 + 2] + lnred_q[t * 4 + 3];
        float mu = s * (1.0f / 512.0f);
        float var = q * (1.0f / 512.0f) - mu * mu;
        lnmv[t * 2] = mu;
        lnmv[t * 2 + 1] = rsqrtf(var + EPSV);
    }
    __syncthreads();

    // normalize + relu + (store fp8 packed) ; invalid rows forced to 0 (masked)
#pragma unroll
    for (int fm = 0; fm < 4; ++fm)
#pragma unroll
        for (int j = 0; j < 4; ++j) {
            int rloc = wm * 64 + fm * 16 + lg * 4 + j;
            long rglob = row0 + rloc;
            bool ok = rglob < NPTS;
            float mu = lnmv[rloc * 2], rstd = lnmv[rloc * 2 + 1];
#pragma unroll
            for (int fn = 0; fn < 8; ++fn) {
                float y = fmaxf((acc[fm][fn][j] - mu) * rstd * gv[fn] + bv[fn], 0.0f);
                acc[fm][fn][j] = ok ? y : 0.0f;
            }
            if (STORE && ok) {
                // col = wn*128 + fn*16 + ln15 ; kt = col>>6 ; byte-in-row = col&63
#pragma unroll
                for (int p = 0; p < 4; ++p) {
                    unsigned u = (unsigned)__builtin_amdgcn_cvt_pk_fp8_f32(
                        acc[fm][2 * p][j], acc[fm][2 * p + 1][j], 0, false);
                    int fnA = 2 * p, fnB = 2 * p + 1;
                    Hout[((long)(wn * 2 + (fnA >> 2)) * NPTS_PAD + rglob) * 64 +
                         (fnA & 3) * 16 + ln15] = (unsigned char)(u & 0xff);
                    Hout[((long)(wn * 2 + (fnB >> 2)) * NPTS_PAD + rglob) * 64 +
                         (fnB & 3) * 16 + ln15] = (unsigned char)((u >> 8) & 0xff);
                }
            }
        }

    // column partials over the block's 128 rows (sum or max)
    float cp[8];
#pragma unroll
    for (int fn = 0; fn < 8; ++fn) {
        float p = 0.f;
#pragma unroll
        for (int fm = 0; fm < 4; ++fm)
#pragma unroll
            for (int j = 0; j < 4; ++j) {
                float v = acc[fm][fn][j];
                p = (REDOP == 0) ? (p + v) : fmaxf(p, v);
            }
        cp[fn] = p;
    }
#pragma unroll
    for (int m = 16; m < 64; m <<= 1)
#pragma unroll
        for (int fn = 0; fn < 8; ++fn) {
            float o = __shfl_xor(cp[fn], m);
            cp[fn] = (REDOP == 0) ? (cp[fn] + o) : fmaxf(cp[fn], o);
        }
    if (lg == 0) {
#pragma unroll
        for (int fn = 0; fn < 8; ++fn)
            csred[wm * 512 + wn * 128 + fn * 16 + ln15] = cp[fn];
    }
    __syncthreads();
    {
        float a0 = csred[t], a1 = csred[512 + t];
        red_out[(long)blockIdx.x * 512 + t] = (REDOP == 0) ? (a0 + a1) : fmaxf(a0, a1);
    }
}

extern "C" void kernel_launch(void* const* d_in, const int* in_sizes, int n_in,
                              void* d_out, int out_size, void* d_ws, size_t ws_size,
                              hipStream_t stream) {
    const float* in_set = (const float*)d_in[0];
    const float* A0 = (const float*)d_in[1];
    const float* B0 = (const float*)d_in[2];
    const float* A1 = (const float*)d_in[3];
    const float* B1 = (const float*)d_in[4];
    const float* A2 = (const float*)d_in[5];
    const float* B2 = (const float*)d_in[6];
    const float* ga = (const float*)d_in[7];
    const float* be = (const float*)d_in[8];
    const float* ow = (const float*)d_in[9];
    const float* ob = (const float*)d_in[10];
    float* outp = (float*)d_out;
    char* ws = (char*)d_ws;

    unsigned char* in_f8 = (unsigned char*)(ws + OFF_INBF);
    unsigned char* W0p = (unsigned char*)(ws + OFF_W0);
    unsigned char* W1p = (unsigned char*)(ws + OFF_W1);
    unsigned char* W2p = (unsigned char*)(ws + OFF_W2);
    float* c0 = (float*)(ws + OFF_C0);
    float* c1 = (float*)(ws + OFF_C1);
    float* c2 = (float*)(ws + OFF_C2);
    float* parts = (float*)(ws + OFF_PARTS);
    float* parts2 = (float*)(ws + OFF_PARTS2);
    float* parts3 = (float*)(ws + OFF_PARTS3);
    unsigned char* h1 = (unsigned char*)(ws + OFF_H1);
    unsigned char* h2 = (unsigned char*)(ws + OFF_H2);

    const int nblk = (NPTS + 127) / 128;  // 782

    cvt_pack_kernel<<<1024, 256, 0, stream>>>(in_set, in_f8);
    wdiff_pack_kernel<<<4, 256, 0, stream>>>(A0, B0, W0p, 128);
    wdiff_pack_kernel<<<16, 256, 0, stream>>>(A1, B1, W1p, 512);
    wdiff_pack_kernel<<<16, 256, 0, stream>>>(A2, B2, W2p, 512);

    // c0 = colsum(in_set) @ B0^T  (all fp32 — the numerically critical path), wide+shallow
    colsum_in_kernel<<<512, 256, 0, stream>>>(in_set, parts);                       // [512][128]
    part_reduceW_kernel<<<64, 128, 0, stream>>>(parts, 512, 128, 0, parts2);        // [64][128]
    part_reduceW_kernel<<<8, 128, 0, stream>>>(parts2, 64, 128, 0, parts3);         // [8][128]
    gemv_fold_kernel<<<512, 64, 0, stream>>>(parts3, 128, B0, nullptr, 0, c0);

    layer_kernel<128, true, 0><<<nblk, 512, 0, stream>>>(in_f8, W0p, c0, ga, be, h1, parts);
    part_reduceW_kernel<<<64, 512, 0, stream>>>(parts, nblk, 512, 0, parts2);
    part_reduceW_kernel<<<8, 512, 0, stream>>>(parts2, 64, 512, 0, parts3);
    gemv_fold_kernel<<<512, 64, 0, stream>>>(parts3, 512, B1, nullptr, 0, c1);

    layer_kernel<512, true, 0><<<nblk, 512, 0, stream>>>(h1, W1p, c1, ga, be, h2, parts);
    part_reduceW_kernel<<<64, 512, 0, stream>>>(parts, nblk, 512, 0, parts2);
    part_reduceW_kernel<<<8, 512, 0, stream>>>(parts2, 64, 512, 0, parts3);
    gemv_fold_kernel<<<512, 64, 0, stream>>>(parts3, 512, B2, nullptr, 0, c2);

    // layer 2: no h3 store; fused column-max partials; final = (max-fold) @ ow^T + ob
    layer_kernel<512, false, 1><<<nblk, 512, 0, stream>>>(h2, W2p, c2, ga, be, nullptr, parts);
    part_reduceW_kernel<<<64, 512, 0, stream>>>(parts, nblk, 512, 1, parts2);
    part_reduceW_kernel<<<8, 512, 0, stream>>>(parts2, 64, 512, 1, parts3);
    gemv_fold_kernel<<<256, 64, 0, stream>>>(parts3, 512, ow, ob, 1, outp);
}